// Round 14
// baseline (230.022 us; speedup 1.0000x reference)
//
#include <hip/hip_runtime.h>
#include <math.h>

// Problem dims
#define NN   2048      // nodes
#define BB   64        // batch
#define FF   48        // in features
#define EE   65536     // edges per graph
#define CC   7         // out channels
#define HH   20        // hidden

// ---- ws layout (bytes), ws_size = 256 MiB ----
#define OFF_DEG      0u
#define OFF_CURSOR   32768u
#define ZBYTES       65536u
#define OFF_DINV     65536u            // float[4][N]
#define OFF_ROWPTR   98304u            // int[4][N+1]
#define OFF_CSRC     131584u           // int[4][E]
#define OFF_CSRW     1180160u          // float[4][E]
#define OFF_H1       2228736u          // 6 x bf16[N][20][B] (u16) = 6 x 5.24MB
#define OFF_P        OFF_H1            // 6 x float[N][7][B], overlays H1 (dead at spmm2)
#define OFF_Y        65143296u         // 6 x bf16[N][20][B] (u16); init = xV+b, act in place
#define OFF_H2       128057856u        // 6 x bf16[N][8][B] (u16, padded to 8 ch) = 6 x 2MB
#define OFF_YV       153223680u        // 6 x float[N][7][B]
#define OFF_T        175243776u        // float[N][40][B] 21MB
// end = 196,215,296 B < 256 MiB

#define H1S  2621440u   // elements per branch in H1(u16) / Y(u16)
#define H2S  1048576u   // u16 elements per branch in H2 (padded)
#define YVS  917504u    // floats per branch in YV / P

typedef __attribute__((ext_vector_type(8))) short bf16x8;
typedef __attribute__((ext_vector_type(4))) float f32x4;
#define MFMA32 __builtin_amdgcn_mfma_f32_16x16x32_bf16

__device__ __forceinline__ unsigned short bf16_rne(float x) {
    unsigned u = __float_as_uint(x);
    u += 0x7fffu + ((u >> 16) & 1u);
    return (unsigned short)(u >> 16);
}
__device__ __forceinline__ float4 ubf4(uint2 u) {
    float4 r;
    r.x = __uint_as_float(u.x << 16);
    r.y = __uint_as_float(u.x & 0xffff0000u);
    r.z = __uint_as_float(u.y << 16);
    r.w = __uint_as_float(u.y & 0xffff0000u);
    return r;
}

// ---------------- CSR build ----------------
__global__ __launch_bounds__(256) void count_deg_kernel(
    const int* __restrict__ c0, const int* __restrict__ c1,
    const int* __restrict__ c2, const int* __restrict__ c3, int* __restrict__ deg)
{
    int idx = blockIdx.x * 256 + threadIdx.x;          // 4*E threads
    int g = idx >> 16, e = idx & 0xFFFF;
    const int* cp = g == 0 ? c0 : g == 1 ? c1 : g == 2 ? c2 : c3;
    atomicAdd(&deg[(g << 11) + cp[e]], 1);
}

__global__ __launch_bounds__(256) void scan_dinv_kernel(
    const int* __restrict__ deg, int* __restrict__ rowptr, float* __restrict__ dinv)
{
    int g = blockIdx.x, t = threadIdx.x;
    __shared__ int part[256];
    const int* d = deg + g * NN;
    int loc[8]; int s = 0;
#pragma unroll
    for (int j = 0; j < 8; ++j) { loc[j] = d[t * 8 + j]; s += loc[j]; }
    part[t] = s; __syncthreads();
    for (int off = 1; off < 256; off <<= 1) {
        int v = (t >= off) ? part[t - off] : 0;
        __syncthreads();
        part[t] += v;
        __syncthreads();
    }
    int run = (t > 0) ? part[t - 1] : 0;
    int* rp = rowptr + g * (NN + 1);
#pragma unroll
    for (int j = 0; j < 8; ++j) {
        int n = t * 8 + j;
        rp[n] = run; run += loc[j];
        dinv[g * NN + n] = loc[j] > 0 ? 1.0f / sqrtf((float)loc[j]) : 0.0f;
    }
    if (t == 255) rp[NN] = run;
}

__global__ __launch_bounds__(256) void fill_csr_kernel(
    const int* __restrict__ r0, const int* __restrict__ c0,
    const int* __restrict__ r1, const int* __restrict__ c1,
    const int* __restrict__ r2, const int* __restrict__ c2,
    const int* __restrict__ r3, const int* __restrict__ c3,
    const int* __restrict__ rowptr, int* __restrict__ cursor,
    const float* __restrict__ dinv, int* __restrict__ csrc, float* __restrict__ cw)
{
    int idx = blockIdx.x * 256 + threadIdx.x;
    int g = idx >> 16, e = idx & 0xFFFF;
    const int* rp = g == 0 ? r0 : g == 1 ? r1 : g == 2 ? r2 : r3;
    const int* cp = g == 0 ? c0 : g == 1 ? c1 : g == 2 ? c2 : c3;
    int r = rp[e], c = cp[e];
    int pos = atomicAdd(&cursor[(g << 11) + c], 1);
    int o = rowptr[g * (NN + 1) + c] + pos;
    csrc[(g << 16) + o] = r;
    cw[(g << 16) + o] = dinv[(g << 11) + r] * dinv[(g << 11) + c];
}

// ---------------- unified MFMA GEMM (7 branches) ----------------
// br<6: [M,48]@[48,20] x2 -> H1 bf16 + Y bf16.  br==6: [M,48]@[48,40] -> T f32.
// X staged in LDS as BF16 [256 rows][48] padded to 56 u16 (28.7KB -> 5 blocks/CU;
// frag = ONE ds_read_b128 per K-chunk, zero VALU; banks 2-way max = free).
// A frag: lane row=l&15, k = 32c + (l>>4)*8 + j; B frag: col=l&15, same k-map.
// C/D: col=lane&15, row=(lane>>4)*4+reg [m89-verified].
__global__ __launch_bounds__(256) void gemm48_mfma(
    const float* __restrict__ X0, const float* __restrict__ X1,
    const float* __restrict__ X2, const float* __restrict__ X3,
    const float* __restrict__ X4, const float* __restrict__ X5,
    const float* __restrict__ W1, const float* __restrict__ V1,
    const float* __restrict__ b1,
    const float* __restrict__ Wlt, const float* __restrict__ blt,
    unsigned short* __restrict__ H1u, unsigned short* __restrict__ Yu,
    float* __restrict__ T)
{
    int br = blockIdx.y;
    const float* X = br == 0 ? X0 : br == 1 ? X1 : br == 2 ? X2 :
                     br == 3 ? X3 : br == 4 ? X4 : X5;

    __shared__ unsigned short xs[256 * 56];   // 28672 B, row stride 112 B
    int t = threadIdx.x;
    const float4* Xv = reinterpret_cast<const float4*>(X) + (size_t)blockIdx.x * 3072;

    // coalesced stage: 3072 float4s, converted to bf16 once
#pragma unroll
    for (int i = 0; i < 12; ++i) {
        int fl4 = i * 256 + t;
        float4 v = Xv[fl4];
        int r = fl4 / 12, fq = fl4 % 12;
        uint2 pk;
        pk.x = (unsigned)bf16_rne(v.x) | ((unsigned)bf16_rne(v.y) << 16);
        pk.y = (unsigned)bf16_rne(v.z) | ((unsigned)bf16_rne(v.w) << 16);
        *reinterpret_cast<uint2*>(&xs[r * 56 + fq * 4]) = pk;
    }

    int w = t >> 6, lane = t & 63;
    int node = blockIdx.x * 4 + w;
    int col = lane & 15;
    int grp = lane >> 4;

    if (br < 6) {
        const float* Wa = W1 + br * 960;
        const float* Wb = V1 + br * 960;
        // B-frags: [chunk][ntile] for W and V
        bf16x8 bw[2][2], bv[2][2];
#pragma unroll
        for (int c = 0; c < 2; ++c)
#pragma unroll
            for (int nt = 0; nt < 2; ++nt) {
                int n = nt * 16 + col;
#pragma unroll
                for (int j = 0; j < 8; ++j) {
                    int k = c * 32 + grp * 8 + j;
                    float vw = 0.0f, vv = 0.0f;
                    if (n < 20 && k < 48) { vw = Wa[k * 20 + n]; vv = Wb[k * 20 + n]; }
                    bw[c][nt][j] = (short)bf16_rne(vw);
                    bv[c][nt][j] = (short)bf16_rne(vv);
                }
            }
        float bias0 = b1[br * 20 + col];
        float bias1 = col < 4 ? b1[br * 20 + 16 + col] : 0.0f;
        __syncthreads();

#pragma unroll
        for (int tb = 0; tb < 4; ++tb) {
            int b0 = tb * 16;
            int row = w * 64 + b0 + col;
            const unsigned short* xr = &xs[row * 56];

            bf16x8 a0 = *reinterpret_cast<const bf16x8*>(xr + grp * 8);
            bf16x8 a1 = {0, 0, 0, 0, 0, 0, 0, 0};
            if (grp < 2)
                a1 = *reinterpret_cast<const bf16x8*>(xr + 32 + grp * 8);

            f32x4 aw0 = {0,0,0,0}, aw1 = {0,0,0,0}, av0 = {0,0,0,0}, av1 = {0,0,0,0};
            aw0 = MFMA32(a0, bw[0][0], aw0, 0, 0, 0);
            aw1 = MFMA32(a0, bw[0][1], aw1, 0, 0, 0);
            av0 = MFMA32(a0, bv[0][0], av0, 0, 0, 0);
            av1 = MFMA32(a0, bv[0][1], av1, 0, 0, 0);
            aw0 = MFMA32(a1, bw[1][0], aw0, 0, 0, 0);
            aw1 = MFMA32(a1, bw[1][1], aw1, 0, 0, 0);
            av0 = MFMA32(a1, bv[1][0], av0, 0, 0, 0);
            av1 = MFMA32(a1, bv[1][1], av1, 0, 0, 0);

            size_t base = (size_t)br * H1S + (size_t)node * 1280 + b0 + grp * 4;
            uint2 pk;
            pk.x = (unsigned)bf16_rne(aw0[0]) | ((unsigned)bf16_rne(aw0[1]) << 16);
            pk.y = (unsigned)bf16_rne(aw0[2]) | ((unsigned)bf16_rne(aw0[3]) << 16);
            *reinterpret_cast<uint2*>(H1u + base + (size_t)col * 64) = pk;
            pk.x = (unsigned)bf16_rne(av0[0] + bias0) | ((unsigned)bf16_rne(av0[1] + bias0) << 16);
            pk.y = (unsigned)bf16_rne(av0[2] + bias0) | ((unsigned)bf16_rne(av0[3] + bias0) << 16);
            *reinterpret_cast<uint2*>(Yu + base + (size_t)col * 64) = pk;
            if (col < 4) {
                int k2 = 16 + col;
                pk.x = (unsigned)bf16_rne(aw1[0]) | ((unsigned)bf16_rne(aw1[1]) << 16);
                pk.y = (unsigned)bf16_rne(aw1[2]) | ((unsigned)bf16_rne(aw1[3]) << 16);
                *reinterpret_cast<uint2*>(H1u + base + (size_t)k2 * 64) = pk;
                pk.x = (unsigned)bf16_rne(av1[0] + bias1) | ((unsigned)bf16_rne(av1[1] + bias1) << 16);
                pk.y = (unsigned)bf16_rne(av1[2] + bias1) | ((unsigned)bf16_rne(av1[3] + bias1) << 16);
                *reinterpret_cast<uint2*>(Yu + base + (size_t)k2 * 64) = pk;
            }
        }
    } else {
        // o_lt: [M,48]@[48,40] (N padded to 48 -> 3 ntiles), out T f32 + blt bias
        bf16x8 bw[2][3];
#pragma unroll
        for (int c = 0; c < 2; ++c)
#pragma unroll
            for (int nt = 0; nt < 3; ++nt) {
                int n = nt * 16 + col;
#pragma unroll
                for (int j = 0; j < 8; ++j) {
                    int k = c * 32 + grp * 8 + j;
                    float vw = 0.0f;
                    if (n < 40 && k < 48) vw = Wlt[k * 40 + n];
                    bw[c][nt][j] = (short)bf16_rne(vw);
                }
            }
        float bias[3];
#pragma unroll
        for (int nt = 0; nt < 3; ++nt) {
            int n = nt * 16 + col;
            bias[nt] = n < 40 ? blt[n] : 0.0f;
        }
        __syncthreads();

#pragma unroll
        for (int tb = 0; tb < 4; ++tb) {
            int b0 = tb * 16;
            int row = w * 64 + b0 + col;
            const unsigned short* xr = &xs[row * 56];

            bf16x8 a0 = *reinterpret_cast<const bf16x8*>(xr + grp * 8);
            bf16x8 a1 = {0, 0, 0, 0, 0, 0, 0, 0};
            if (grp < 2)
                a1 = *reinterpret_cast<const bf16x8*>(xr + 32 + grp * 8);

            f32x4 ac[3] = {{0,0,0,0},{0,0,0,0},{0,0,0,0}};
#pragma unroll
            for (int nt = 0; nt < 3; ++nt) {
                ac[nt] = MFMA32(a0, bw[0][nt], ac[nt], 0, 0, 0);
                ac[nt] = MFMA32(a1, bw[1][nt], ac[nt], 0, 0, 0);
            }

            size_t base = (size_t)node * 2560 + b0 + grp * 4;
#pragma unroll
            for (int nt = 0; nt < 3; ++nt) {
                int n = nt * 16 + col;
                if (n < 40) {
                    float4 v = { ac[nt][0] + bias[nt], ac[nt][1] + bias[nt],
                                 ac[nt][2] + bias[nt], ac[nt][3] + bias[nt] };
                    *reinterpret_cast<float4*>(&T[base + (size_t)n * 64]) = v;
                }
            }
        }
    }
}

__device__ __forceinline__ void fma4(float4& a, float w, const float4 v) {
    a.x += w * v.x; a.y += w * v.y; a.z += w * v.z; a.w += w * v.w;
}
__device__ __forceinline__ float gelu_elu(float v) {
    float g = 0.5f * v * (1.0f + erff(v * 0.70710678118654752f));   // exact GELU
    return g > 0.0f ? g : expm1f(g);                                 // ELU
}

// ---------------- batched SpMM1 + GELU + ELU, bf16 gather, in-place on bf16 Y ----------------
// XCD-pinned slices; scalarized CSR; 8-deep gather of uint2 (4 bf16).
__global__ __launch_bounds__(256) void spmm1_all(
    const uint2* __restrict__ H1u, uint2* __restrict__ Y,
    const int* __restrict__ rowptr, const int* __restrict__ csrc, const float* __restrict__ csrw)
{
    int bid = blockIdx.x;
    int w0 = (bid & 7) * 1920 + (bid >> 3);   // 0..15359
    int sl = w0 >> 9;                          // 0..29
    int ng = w0 & 511;
    int br = sl / 5, q = sl - br * 5;

    int gg = br == 1 ? 1 : br == 2 ? 2 : br == 5 ? 3 : 0;
    const int*   rp  = rowptr + gg * (NN + 1);
    const int*   src = csrc + (size_t)gg * EE;
    const float* wts = csrw + (size_t)gg * EE;
    const uint2* h = H1u + (size_t)br * (H1S / 4);   // 320 uint2 per node-row
    uint2*       y = Y + (size_t)br * (H1S / 4);     // 320 uint2 per node-row

    int wv = __builtin_amdgcn_readfirstlane(threadIdx.x >> 6);
    int lane = threadIdx.x & 63;
    int n = ng * 4 + wv;                       // wave-uniform -> scalar CSR loads
    int off = q * 64 + lane;
    int s0 = rp[n], s1 = rp[n + 1];

    float4 a0 = {0,0,0,0}, a1 = {0,0,0,0}, a2 = {0,0,0,0}, a3 = {0,0,0,0};
    int e = s0;
    for (; e + 8 <= s1; e += 8) {
        int   iA = src[e],   iB = src[e+1], iC = src[e+2], iD = src[e+3];
        int   iE = src[e+4], iF = src[e+5], iG = src[e+6], iH = src[e+7];
        float wA = wts[e],   wB = wts[e+1], wC = wts[e+2], wD = wts[e+3];
        float wE = wts[e+4], wF = wts[e+5], wG = wts[e+6], wH = wts[e+7];
        uint2 u0 = h[iA * 320 + off];
        uint2 u1 = h[iB * 320 + off];
        uint2 u2 = h[iC * 320 + off];
        uint2 u3 = h[iD * 320 + off];
        uint2 u4 = h[iE * 320 + off];
        uint2 u5 = h[iF * 320 + off];
        uint2 u6 = h[iG * 320 + off];
        uint2 u7 = h[iH * 320 + off];
        fma4(a0, wA, ubf4(u0)); fma4(a1, wB, ubf4(u1));
        fma4(a2, wC, ubf4(u2)); fma4(a3, wD, ubf4(u3));
        fma4(a0, wE, ubf4(u4)); fma4(a1, wF, ubf4(u5));
        fma4(a2, wG, ubf4(u6)); fma4(a3, wH, ubf4(u7));
    }
    for (; e + 2 <= s1; e += 2) {
        uint2 u0 = h[src[e] * 320 + off];
        uint2 u1 = h[src[e+1] * 320 + off];
        fma4(a0, wts[e], ubf4(u0)); fma4(a1, wts[e+1], ubf4(u1));
    }
    if (e < s1) fma4(a0, wts[e], ubf4(h[src[e] * 320 + off]));
    a0.x += a1.x + a2.x + a3.x;
    a0.y += a1.y + a2.y + a3.y;
    a0.z += a1.z + a2.z + a3.z;
    a0.w += a1.w + a2.w + a3.w;

    size_t b0 = (size_t)n * 320 + off;
    float4 xv = ubf4(y[b0]);
    float4 r;
    r.x = gelu_elu(a0.x + xv.x);
    r.y = gelu_elu(a0.y + xv.y);
    r.z = gelu_elu(a0.z + xv.z);
    r.w = gelu_elu(a0.w + xv.w);
    uint2 pk;
    pk.x = (unsigned)bf16_rne(r.x) | ((unsigned)bf16_rne(r.y) << 16);
    pk.y = (unsigned)bf16_rne(r.z) | ((unsigned)bf16_rne(r.w) << 16);
    y[b0] = pk;
}

// ---------------- batched dual GEMM2: [M,20]@[20,7] x2; Y bf16 in, H2 bf16 out ----------------
__global__ __launch_bounds__(256) void gemm2_all(
    const unsigned short* __restrict__ Yu, const float* __restrict__ W2,
    const float* __restrict__ V2, const float* __restrict__ b2,
    unsigned short* __restrict__ H2u, float* __restrict__ YV)
{
    int br = blockIdx.y;
    const unsigned short* y = Yu + (size_t)br * H1S;
    unsigned short* h2 = H2u + (size_t)br * H2S;
    float* yv = YV + (size_t)br * YVS;
    __shared__ float w2s[140], v2s[140], b2s[7];
    int t = threadIdx.x;
    if (t < 140) { w2s[t] = W2[br * 140 + t]; v2s[t] = V2[br * 140 + t]; }
    if (t < 7) b2s[t] = b2[br * 7 + t];
    __syncthreads();
    int wv = __builtin_amdgcn_readfirstlane(t >> 6), b = t & 63;
    int n = blockIdx.x * 4 + wv;
    size_t yb = (size_t)n * 1280 + b;
    float yr[20];
#pragma unroll
    for (int k = 0; k < 20; ++k)
        yr[k] = __uint_as_float((unsigned)y[yb + (size_t)k * 64] << 16);
    float a[7] = {}, v[7] = {};
#pragma unroll
    for (int k = 0; k < 20; ++k) {
        float yk = yr[k];
#pragma unroll
        for (int c = 0; c < 7; ++c) {
            a[c] += yk * w2s[k * 7 + c];
            v[c] += yk * v2s[k * 7 + c];
        }
    }
    size_t hb = (size_t)n * 512 + b;
#pragma unroll
    for (int c = 0; c < 7; ++c) h2[hb + (size_t)c * 64] = bf16_rne(a[c]);
    h2[hb + 7 * 64] = 0;                          // padding channel
    size_t vb = (size_t)n * 448 + b;
#pragma unroll
    for (int c = 0; c < 7; ++c) yv[vb + (size_t)c * 64] = v[c] + b2s[c];
}

// ---------------- batched SpMM2 + ReLU + softmax(B) -> per-branch P ----------------
// XCD-pinned; scalarized CSR; 8-deep bf16 gather. Row = [8 ch][64 b] u16 = 128 uint2.
__global__ __launch_bounds__(256) void spmm2_all(
    const uint2* __restrict__ H2u, const float* __restrict__ YV,
    const int* __restrict__ rowptr, const int* __restrict__ csrc, const float* __restrict__ csrw,
    float* __restrict__ P)
{
    int bid = blockIdx.x;
    int w0 = (bid & 7) * 768 + (bid >> 3);    // 0..6143
    int sl = w0 >> 9;                          // 0..11
    int ng = w0 & 511;
    int br = sl >> 1, hh = sl & 1;

    int gg = br == 1 ? 1 : br == 2 ? 2 : br == 5 ? 3 : 0;
    const int*   rp  = rowptr + gg * (NN + 1);
    const int*   src = csrc + (size_t)gg * EE;
    const float* wts = csrw + (size_t)gg * EE;
    const uint2* h2 = H2u + (size_t)br * (H2S / 4);   // 128 uint2 per node-row
    const float* yv = YV + (size_t)br * YVS;
    float* p = P + (size_t)br * YVS;

    int wv = __builtin_amdgcn_readfirstlane(threadIdx.x >> 6);
    int lane = threadIdx.x & 63;
    int n = ng * 4 + wv;
    int s = hh * 64 + lane;          // uint2 slot in the 128-slot row
    int c = s >> 4;                  // 0..7 (7 = padding)
    int bq = lane & 15;              // b quad
    int s0 = rp[n], s1 = rp[n + 1];

    float4 a0 = {0,0,0,0}, a1 = {0,0,0,0}, a2 = {0,0,0,0}, a3 = {0,0,0,0};
    int e = s0;
    for (; e + 8 <= s1; e += 8) {
        int   iA = src[e],   iB = src[e+1], iC = src[e+2], iD = src[e+3];
        int   iE = src[e+4], iF = src[e+5], iG = src[e+6], iH = src[e+7];
        float wA = wts[e],   wB = wts[e+1], wC = wts[e+2], wD = wts[e+3];
        float wE = wts[e+4], wF = wts[e+5], wG = wts[e+6], wH = wts[e+7];
        uint2 u0 = h2[iA * 128 + s];
        uint2 u1 = h2[iB * 128 + s];
        uint2 u2 = h2[iC * 128 + s];
        uint2 u3 = h2[iD * 128 + s];
        uint2 u4 = h2[iE * 128 + s];
        uint2 u5 = h2[iF * 128 + s];
        uint2 u6 = h2[iG * 128 + s];
        uint2 u7 = h2[iH * 128 + s];
        fma4(a0, wA, ubf4(u0)); fma4(a1, wB, ubf4(u1));
        fma4(a2, wC, ubf4(u2)); fma4(a3, wD, ubf4(u3));
        fma4(a0, wE, ubf4(u4)); fma4(a1, wF, ubf4(u5));
        fma4(a2, wG, ubf4(u6)); fma4(a3, wH, ubf4(u7));
    }
    for (; e < s1; ++e) fma4(a0, wts[e], ubf4(h2[src[e] * 128 + s]));
    a0.x += a1.x + a2.x + a3.x;
    a0.y += a1.y + a2.y + a3.y;
    a0.z += a1.z + a2.z + a3.z;
    a0.w += a1.w + a2.w + a3.w;

    float4 z = {0,0,0,0};
    if (c < 7) {
        float4 yvv = *reinterpret_cast<const float4*>(&yv[(size_t)n * 448 + c * 64 + bq * 4]);
        z.x = fmaxf(a0.x + yvv.x, 0.0f);
        z.y = fmaxf(a0.y + yvv.y, 0.0f);
        z.z = fmaxf(a0.z + yvv.z, 0.0f);
        z.w = fmaxf(a0.w + yvv.w, 0.0f);
    }
    float m = fmaxf(fmaxf(z.x, z.y), fmaxf(z.z, z.w));
#pragma unroll
    for (int o = 8; o > 0; o >>= 1) m = fmaxf(m, __shfl_xor(m, o, 64));
    float4 pz;
    pz.x = expf(z.x - m); pz.y = expf(z.y - m);
    pz.z = expf(z.z - m); pz.w = expf(z.w - m);
    float sm = pz.x + pz.y + pz.z + pz.w;
#pragma unroll
    for (int o = 8; o > 0; o >>= 1) sm += __shfl_xor(sm, o, 64);
    float inv = 1.0f / sm;
    if (c < 7) {
        float4 r = { pz.x * inv, pz.y * inv, pz.z * inv, pz.w * inv };
        *reinterpret_cast<float4*>(&p[(size_t)n * 448 + c * 64 + bq * 4]) = r;
    }
}

// ---------------- wave softmax over 64 lanes (batch axis) ----------------
__device__ __forceinline__ void wave_softmax7(float* z)
{
#pragma unroll
    for (int c = 0; c < 7; ++c) {
        float m = z[c];
#pragma unroll
        for (int o = 32; o > 0; o >>= 1) m = fmaxf(m, __shfl_xor(m, o, 64));
        float p = expf(z[c] - m);
        float s = p;
#pragma unroll
        for (int o = 32; o > 0; o >>= 1) s += __shfl_xor(s, o, 64);
        z[c] = p / s;
    }
}

// ---------------- final: o_lt tail, dense+gnn heads, output [N][C][B] ----------------
__global__ __launch_bounds__(256) void combine_kernel(
    const float* __restrict__ T, const float* __restrict__ P,
    const float* __restrict__ Wl2, const float* __restrict__ bl2,
    const float* __restrict__ Wd, const float* __restrict__ bd,
    const float* __restrict__ Wg, const float* __restrict__ bg,
    float* __restrict__ out)
{
    __shared__ float wl2s[280], bl2s[7], wds[49], bds[7], wgs[49], bgs[7];
    int t = threadIdx.x;
    for (int i = t; i < 280; i += 256) wl2s[i] = Wl2[i];
    if (t < 49) { wds[t] = Wd[t]; wgs[t] = Wg[t]; }
    if (t < 7) { bl2s[t] = bl2[t]; bds[t] = bd[t]; bgs[t] = bg[t]; }
    __syncthreads();

    int wv = t >> 6, b = t & 63;
    int n = blockIdx.x * 4 + wv;
    size_t rbase = (size_t)n * 2560 + b;   // T is [n][40][b]
    float tr[40];
#pragma unroll
    for (int j = 0; j < 40; ++j) tr[j] = T[rbase + (size_t)j * 64];

    float u[7];
#pragma unroll
    for (int c = 0; c < 7; ++c) u[c] = bl2s[c];
    for (int j = 0; j < 40; ++j) {
        float tv = tr[j];
#pragma unroll
        for (int c = 0; c < 7; ++c) u[c] += tv * wl2s[j * 7 + c];
    }
    wave_softmax7(u);   // o_lt

    size_t sbase = (size_t)n * 448 + b;
    float sd[7], sg[7];
#pragma unroll
    for (int c = 0; c < 7; ++c) {
        size_t o = sbase + (size_t)c * 64;
        sg[c] = P[o] + P[YVS + o] + P[2 * YVS + o] + P[3 * YVS + o] + P[4 * YVS + o];
        sd[c] = 2.0f * P[5 * YVS + o] + 2.0f * u[c];
    }
    float dv[7];
#pragma unroll
    for (int c = 0; c < 7; ++c) dv[c] = bds[c];
#pragma unroll
    for (int c2 = 0; c2 < 7; ++c2) {
        float s = sd[c2];
#pragma unroll
        for (int c = 0; c < 7; ++c) dv[c] += s * wds[c2 * 7 + c];
    }
    wave_softmax7(dv);  // out_dense

    float gv[7];
#pragma unroll
    for (int c = 0; c < 7; ++c) gv[c] = bgs[c];
#pragma unroll
    for (int c2 = 0; c2 < 7; ++c2) {
        float s = sg[c2];
#pragma unroll
        for (int c = 0; c < 7; ++c) gv[c] += s * wgs[c2 * 7 + c];
    }
    wave_softmax7(gv);  // out_gnn

    size_t ob = (size_t)n * 448 + b;
#pragma unroll
    for (int c = 0; c < 7; ++c) out[ob + (size_t)c * 64] = dv[c] + gv[c];
}

// ---------------- host ----------------
extern "C" void kernel_launch(void* const* d_in, const int* in_sizes, int n_in,
                              void* d_out, int out_size, void* d_ws, size_t ws_size,
                              hipStream_t stream)
{
    (void)in_sizes; (void)n_in; (void)out_size; (void)ws_size;
    const int* e0 = (const int*)d_in[0];
    const int* e1 = (const int*)d_in[1];
    const int* e2 = (const int*)d_in[2];
    const int* e3 = (const int*)d_in[3];
    const float* X0 = (const float*)d_in[4];
    const float* X1 = (const float*)d_in[5];
    const float* X2 = (const float*)d_in[6];
    const float* X3 = (const float*)d_in[7];
    const float* X4 = (const float*)d_in[8];
    const float* X5 = (const float*)d_in[9];
    const float* W1  = (const float*)d_in[10];
    const float* V1  = (const float*)d_in[11];
    const float* b1  = (const float*)d_in[12];
    const float* W2  = (const float*)d_in[13];
    const float* V2  = (const float*)d_in[14];
    const float* b2  = (const float*)d_in[15];
    const float* Wlt = (const float*)d_in[16];
    const float* blt = (const float*)d_in[17];
    const float* Wl2 = (const float*)d_in[18];
    const float* bl2 = (const float*)d_in[19];
    const float* Wd  = (const float*)d_in[20];
    const float* bd  = (const float*)d_in[21];
    const float* Wg  = (const float*)d_in[22];
    const float* bg  = (const float*)d_in[23];

    char* ws = (char*)d_ws;
    int*   deg    = (int*)(ws + OFF_DEG);
    int*   cursor = (int*)(ws + OFF_CURSOR);
    float* dinv   = (float*)(ws + OFF_DINV);
    int*   rowptr = (int*)(ws + OFF_ROWPTR);
    int*   csrc   = (int*)(ws + OFF_CSRC);
    float* csrw   = (float*)(ws + OFF_CSRW);
    unsigned short* H1u = (unsigned short*)(ws + OFF_H1);
    float* Pbuf   = (float*)(ws + OFF_P);
    unsigned short* Yu = (unsigned short*)(ws + OFF_Y);
    unsigned short* H2u = (unsigned short*)(ws + OFF_H2);
    float* YV     = (float*)(ws + OFF_YV);
    float* Tbuf   = (float*)(ws + OFF_T);

    hipMemsetAsync(d_ws, 0, ZBYTES, stream);

    count_deg_kernel<<<1024, 256, 0, stream>>>(e0 + EE, e1 + EE, e2 + EE, e3 + EE, deg);
    scan_dinv_kernel<<<4, 256, 0, stream>>>(deg, rowptr, dinv);
    fill_csr_kernel<<<1024, 256, 0, stream>>>(e0, e0 + EE, e1, e1 + EE, e2, e2 + EE,
                                              e3, e3 + EE, rowptr, cursor, dinv, csrc, csrw);

    gemm48_mfma<<<dim3(512, 7), 256, 0, stream>>>(X0, X1, X2, X3, X4, X5,
                                                  W1, V1, b1, Wlt, blt, H1u, Yu, Tbuf);
    spmm1_all<<<15360, 256, 0, stream>>>((const uint2*)H1u, (uint2*)Yu,
                                         rowptr, csrc, csrw);
    gemm2_all<<<dim3(512, 6), 256, 0, stream>>>(Yu, W2, V2, b2, H2u, YV);
    spmm2_all<<<6144, 256, 0, stream>>>((const uint2*)H2u, YV,
                                        rowptr, csrc, csrw, Pbuf);
    combine_kernel<<<512, 256, 0, stream>>>(Tbuf, Pbuf, Wl2, bl2, Wd, bd, Wg, bg,
                                            (float*)d_out);
}

// Round 15
// 212.173 us; speedup vs baseline: 1.0841x; 1.0841x over previous
//
#include <hip/hip_runtime.h>
#include <math.h>

// Problem dims
#define NN   2048      // nodes
#define BB   64        // batch
#define FF   48        // in features
#define EE   65536     // edges per graph
#define CC   7         // out channels
#define HH   20        // hidden

// ---- ws layout (bytes), ws_size = 256 MiB ----
#define OFF_DEG      0u
#define OFF_CURSOR   32768u
#define ZBYTES       65536u
#define OFF_DINV     65536u            // float[4][N]
#define OFF_ROWPTR   98304u            // int[4][N+1]
#define OFF_CSRC     131584u           // int[4][E]
#define OFF_CSRW     1180160u          // float[4][E]
#define OFF_H1       2228736u          // 6 x bf16[N][20][B] (u16) = 6 x 5.24MB
#define OFF_P        OFF_H1            // 6 x float[N][7][B], overlays H1 (dead at spmm2)
#define OFF_Y        65143296u         // 6 x bf16[N][20][B] (u16); init = xV+b, act in place
#define OFF_H2       128057856u        // 6 x bf16[N][8][B] (u16, padded to 8 ch) = 6 x 2MB
#define OFF_YV       153223680u        // 6 x float[N][7][B]
#define OFF_T        175243776u        // float[N][40][B] 21MB
// end = 196,215,296 B < 256 MiB

#define H1S  2621440u   // elements per branch in H1(u16) / Y(u16)
#define H2S  1048576u   // u16 elements per branch in H2 (padded)
#define YVS  917504u    // floats per branch in YV / P

typedef __attribute__((ext_vector_type(8))) short bf16x8;
typedef __attribute__((ext_vector_type(4))) float f32x4;
#define MFMA32 __builtin_amdgcn_mfma_f32_16x16x32_bf16

__device__ __forceinline__ unsigned short bf16_rne(float x) {
    unsigned u = __float_as_uint(x);
    u += 0x7fffu + ((u >> 16) & 1u);
    return (unsigned short)(u >> 16);
}
__device__ __forceinline__ float4 ubf4(uint2 u) {
    float4 r;
    r.x = __uint_as_float(u.x << 16);
    r.y = __uint_as_float(u.x & 0xffff0000u);
    r.z = __uint_as_float(u.y << 16);
    r.w = __uint_as_float(u.y & 0xffff0000u);
    return r;
}
__device__ __forceinline__ void fma8(float* a, float w, uint4 u) {
    a[0] += w * __uint_as_float(u.x << 16);
    a[1] += w * __uint_as_float(u.x & 0xffff0000u);
    a[2] += w * __uint_as_float(u.y << 16);
    a[3] += w * __uint_as_float(u.y & 0xffff0000u);
    a[4] += w * __uint_as_float(u.z << 16);
    a[5] += w * __uint_as_float(u.z & 0xffff0000u);
    a[6] += w * __uint_as_float(u.w << 16);
    a[7] += w * __uint_as_float(u.w & 0xffff0000u);
}

// ---------------- CSR build ----------------
__global__ __launch_bounds__(256) void count_deg_kernel(
    const int* __restrict__ c0, const int* __restrict__ c1,
    const int* __restrict__ c2, const int* __restrict__ c3, int* __restrict__ deg)
{
    int idx = blockIdx.x * 256 + threadIdx.x;          // 4*E threads
    int g = idx >> 16, e = idx & 0xFFFF;
    const int* cp = g == 0 ? c0 : g == 1 ? c1 : g == 2 ? c2 : c3;
    atomicAdd(&deg[(g << 11) + cp[e]], 1);
}

__global__ __launch_bounds__(256) void scan_dinv_kernel(
    const int* __restrict__ deg, int* __restrict__ rowptr, float* __restrict__ dinv)
{
    int g = blockIdx.x, t = threadIdx.x;
    __shared__ int part[256];
    const int* d = deg + g * NN;
    int loc[8]; int s = 0;
#pragma unroll
    for (int j = 0; j < 8; ++j) { loc[j] = d[t * 8 + j]; s += loc[j]; }
    part[t] = s; __syncthreads();
    for (int off = 1; off < 256; off <<= 1) {
        int v = (t >= off) ? part[t - off] : 0;
        __syncthreads();
        part[t] += v;
        __syncthreads();
    }
    int run = (t > 0) ? part[t - 1] : 0;
    int* rp = rowptr + g * (NN + 1);
#pragma unroll
    for (int j = 0; j < 8; ++j) {
        int n = t * 8 + j;
        rp[n] = run; run += loc[j];
        dinv[g * NN + n] = loc[j] > 0 ? 1.0f / sqrtf((float)loc[j]) : 0.0f;
    }
    if (t == 255) rp[NN] = run;
}

__global__ __launch_bounds__(256) void fill_csr_kernel(
    const int* __restrict__ r0, const int* __restrict__ c0,
    const int* __restrict__ r1, const int* __restrict__ c1,
    const int* __restrict__ r2, const int* __restrict__ c2,
    const int* __restrict__ r3, const int* __restrict__ c3,
    const int* __restrict__ rowptr, int* __restrict__ cursor,
    const float* __restrict__ dinv, int* __restrict__ csrc, float* __restrict__ cw)
{
    int idx = blockIdx.x * 256 + threadIdx.x;
    int g = idx >> 16, e = idx & 0xFFFF;
    const int* rp = g == 0 ? r0 : g == 1 ? r1 : g == 2 ? r2 : r3;
    const int* cp = g == 0 ? c0 : g == 1 ? c1 : g == 2 ? c2 : c3;
    int r = rp[e], c = cp[e];
    int pos = atomicAdd(&cursor[(g << 11) + c], 1);
    int o = rowptr[g * (NN + 1) + c] + pos;
    csrc[(g << 16) + o] = r;
    cw[(g << 16) + o] = dinv[(g << 11) + r] * dinv[(g << 11) + c];
}

// ---------------- unified MFMA GEMM (7 branches) — r14 proven, unchanged ----------------
__global__ __launch_bounds__(256) void gemm48_mfma(
    const float* __restrict__ X0, const float* __restrict__ X1,
    const float* __restrict__ X2, const float* __restrict__ X3,
    const float* __restrict__ X4, const float* __restrict__ X5,
    const float* __restrict__ W1, const float* __restrict__ V1,
    const float* __restrict__ b1,
    const float* __restrict__ Wlt, const float* __restrict__ blt,
    unsigned short* __restrict__ H1u, unsigned short* __restrict__ Yu,
    float* __restrict__ T)
{
    int br = blockIdx.y;
    const float* X = br == 0 ? X0 : br == 1 ? X1 : br == 2 ? X2 :
                     br == 3 ? X3 : br == 4 ? X4 : X5;

    __shared__ unsigned short xs[256 * 56];   // 28672 B, row stride 112 B
    int t = threadIdx.x;
    const float4* Xv = reinterpret_cast<const float4*>(X) + (size_t)blockIdx.x * 3072;

#pragma unroll
    for (int i = 0; i < 12; ++i) {
        int fl4 = i * 256 + t;
        float4 v = Xv[fl4];
        int r = fl4 / 12, fq = fl4 % 12;
        uint2 pk;
        pk.x = (unsigned)bf16_rne(v.x) | ((unsigned)bf16_rne(v.y) << 16);
        pk.y = (unsigned)bf16_rne(v.z) | ((unsigned)bf16_rne(v.w) << 16);
        *reinterpret_cast<uint2*>(&xs[r * 56 + fq * 4]) = pk;
    }

    int w = t >> 6, lane = t & 63;
    int node = blockIdx.x * 4 + w;
    int col = lane & 15;
    int grp = lane >> 4;

    if (br < 6) {
        const float* Wa = W1 + br * 960;
        const float* Wb = V1 + br * 960;
        bf16x8 bw[2][2], bv[2][2];
#pragma unroll
        for (int c = 0; c < 2; ++c)
#pragma unroll
            for (int nt = 0; nt < 2; ++nt) {
                int n = nt * 16 + col;
#pragma unroll
                for (int j = 0; j < 8; ++j) {
                    int k = c * 32 + grp * 8 + j;
                    float vw = 0.0f, vv = 0.0f;
                    if (n < 20 && k < 48) { vw = Wa[k * 20 + n]; vv = Wb[k * 20 + n]; }
                    bw[c][nt][j] = (short)bf16_rne(vw);
                    bv[c][nt][j] = (short)bf16_rne(vv);
                }
            }
        float bias0 = b1[br * 20 + col];
        float bias1 = col < 4 ? b1[br * 20 + 16 + col] : 0.0f;
        __syncthreads();

#pragma unroll
        for (int tb = 0; tb < 4; ++tb) {
            int b0 = tb * 16;
            int row = w * 64 + b0 + col;
            const unsigned short* xr = &xs[row * 56];

            bf16x8 a0 = *reinterpret_cast<const bf16x8*>(xr + grp * 8);
            bf16x8 a1 = {0, 0, 0, 0, 0, 0, 0, 0};
            if (grp < 2)
                a1 = *reinterpret_cast<const bf16x8*>(xr + 32 + grp * 8);

            f32x4 aw0 = {0,0,0,0}, aw1 = {0,0,0,0}, av0 = {0,0,0,0}, av1 = {0,0,0,0};
            aw0 = MFMA32(a0, bw[0][0], aw0, 0, 0, 0);
            aw1 = MFMA32(a0, bw[0][1], aw1, 0, 0, 0);
            av0 = MFMA32(a0, bv[0][0], av0, 0, 0, 0);
            av1 = MFMA32(a0, bv[0][1], av1, 0, 0, 0);
            aw0 = MFMA32(a1, bw[1][0], aw0, 0, 0, 0);
            aw1 = MFMA32(a1, bw[1][1], aw1, 0, 0, 0);
            av0 = MFMA32(a1, bv[1][0], av0, 0, 0, 0);
            av1 = MFMA32(a1, bv[1][1], av1, 0, 0, 0);

            size_t base = (size_t)br * H1S + (size_t)node * 1280 + b0 + grp * 4;
            uint2 pk;
            pk.x = (unsigned)bf16_rne(aw0[0]) | ((unsigned)bf16_rne(aw0[1]) << 16);
            pk.y = (unsigned)bf16_rne(aw0[2]) | ((unsigned)bf16_rne(aw0[3]) << 16);
            *reinterpret_cast<uint2*>(H1u + base + (size_t)col * 64) = pk;
            pk.x = (unsigned)bf16_rne(av0[0] + bias0) | ((unsigned)bf16_rne(av0[1] + bias0) << 16);
            pk.y = (unsigned)bf16_rne(av0[2] + bias0) | ((unsigned)bf16_rne(av0[3] + bias0) << 16);
            *reinterpret_cast<uint2*>(Yu + base + (size_t)col * 64) = pk;
            if (col < 4) {
                int k2 = 16 + col;
                pk.x = (unsigned)bf16_rne(aw1[0]) | ((unsigned)bf16_rne(aw1[1]) << 16);
                pk.y = (unsigned)bf16_rne(aw1[2]) | ((unsigned)bf16_rne(aw1[3]) << 16);
                *reinterpret_cast<uint2*>(H1u + base + (size_t)k2 * 64) = pk;
                pk.x = (unsigned)bf16_rne(av1[0] + bias1) | ((unsigned)bf16_rne(av1[1] + bias1) << 16);
                pk.y = (unsigned)bf16_rne(av1[2] + bias1) | ((unsigned)bf16_rne(av1[3] + bias1) << 16);
                *reinterpret_cast<uint2*>(Yu + base + (size_t)k2 * 64) = pk;
            }
        }
    } else {
        bf16x8 bw[2][3];
#pragma unroll
        for (int c = 0; c < 2; ++c)
#pragma unroll
            for (int nt = 0; nt < 3; ++nt) {
                int n = nt * 16 + col;
#pragma unroll
                for (int j = 0; j < 8; ++j) {
                    int k = c * 32 + grp * 8 + j;
                    float vw = 0.0f;
                    if (n < 40 && k < 48) vw = Wlt[k * 40 + n];
                    bw[c][nt][j] = (short)bf16_rne(vw);
                }
            }
        float bias[3];
#pragma unroll
        for (int nt = 0; nt < 3; ++nt) {
            int n = nt * 16 + col;
            bias[nt] = n < 40 ? blt[n] : 0.0f;
        }
        __syncthreads();

#pragma unroll
        for (int tb = 0; tb < 4; ++tb) {
            int b0 = tb * 16;
            int row = w * 64 + b0 + col;
            const unsigned short* xr = &xs[row * 56];

            bf16x8 a0 = *reinterpret_cast<const bf16x8*>(xr + grp * 8);
            bf16x8 a1 = {0, 0, 0, 0, 0, 0, 0, 0};
            if (grp < 2)
                a1 = *reinterpret_cast<const bf16x8*>(xr + 32 + grp * 8);

            f32x4 ac[3] = {{0,0,0,0},{0,0,0,0},{0,0,0,0}};
#pragma unroll
            for (int nt = 0; nt < 3; ++nt) {
                ac[nt] = MFMA32(a0, bw[0][nt], ac[nt], 0, 0, 0);
                ac[nt] = MFMA32(a1, bw[1][nt], ac[nt], 0, 0, 0);
            }

            size_t base = (size_t)node * 2560 + b0 + grp * 4;
#pragma unroll
            for (int nt = 0; nt < 3; ++nt) {
                int n = nt * 16 + col;
                if (n < 40) {
                    float4 v = { ac[nt][0] + bias[nt], ac[nt][1] + bias[nt],
                                 ac[nt][2] + bias[nt], ac[nt][3] + bias[nt] };
                    *reinterpret_cast<float4*>(&T[base + (size_t)n * 64]) = v;
                }
            }
        }
    }
}

__device__ __forceinline__ float gelu_elu(float v) {
    float g = 0.5f * v * (1.0f + erff(v * 0.70710678118654752f));   // exact GELU
    return g > 0.0f ? g : expm1f(g);                                 // ELU
}
__device__ __forceinline__ void fma4(float4& a, float w, const float4 v) {
    a.x += w * v.x; a.y += w * v.y; a.z += w * v.z; a.w += w * v.w;
}

// ---------------- batched SpMM1 + GELU + ELU, wide bf16 gather ----------------
// Row re-sliced 8k+8k+4k: st<2 -> uint4/lane (1KB/wave/edge), st==2 -> uint2/lane.
// 18 XCD-pinned slices (2.1/2.1/1.05 MB per branch); scalarized CSR; 4-deep gather.
__global__ __launch_bounds__(256) void spmm1_all(
    const unsigned short* __restrict__ H1u, unsigned short* __restrict__ Yu,
    const int* __restrict__ rowptr, const int* __restrict__ csrc, const float* __restrict__ csrw)
{
    int bid = blockIdx.x;
    int w0 = (bid & 7) * 1152 + (bid >> 3);   // 0..9215
    int sl = w0 >> 9;                          // 0..17
    int ng = w0 & 511;
    int br = sl / 3, st = sl - br * 3;

    int gg = br == 1 ? 1 : br == 2 ? 2 : br == 5 ? 3 : 0;
    const int*   rp  = rowptr + gg * (NN + 1);
    const int*   src = csrc + (size_t)gg * EE;
    const float* wts = csrw + (size_t)gg * EE;

    int wv = __builtin_amdgcn_readfirstlane(threadIdx.x >> 6);
    int lane = threadIdx.x & 63;
    int n = ng * 4 + wv;                       // wave-uniform -> scalar CSR loads
    int s0 = rp[n], s1 = rp[n + 1];

    if (st < 2) {
        // k-block st*8..st*8+7: uint4 per lane; row = 160 uint4
        const uint4* h = reinterpret_cast<const uint4*>(H1u + (size_t)br * H1S);
        uint4*       y = reinterpret_cast<uint4*>(Yu + (size_t)br * H1S);
        int off = st * 64 + lane;
        float acc0[8] = {}, acc1[8] = {};
        int e = s0;
        for (; e + 4 <= s1; e += 4) {
            int   iA = src[e],   iB = src[e+1], iC = src[e+2], iD = src[e+3];
            float wA = wts[e],   wB = wts[e+1], wC = wts[e+2], wD = wts[e+3];
            uint4 u0 = h[iA * 160 + off];
            uint4 u1 = h[iB * 160 + off];
            uint4 u2 = h[iC * 160 + off];
            uint4 u3 = h[iD * 160 + off];
            fma8(acc0, wA, u0); fma8(acc1, wB, u1);
            fma8(acc0, wC, u2); fma8(acc1, wD, u3);
        }
        for (; e < s1; ++e) fma8(acc0, wts[e], h[src[e] * 160 + off]);
#pragma unroll
        for (int j = 0; j < 8; ++j) acc0[j] += acc1[j];

        size_t b0 = (size_t)n * 160 + off;
        uint4 yo = y[b0];
        float yv[8];
        yv[0] = __uint_as_float(yo.x << 16); yv[1] = __uint_as_float(yo.x & 0xffff0000u);
        yv[2] = __uint_as_float(yo.y << 16); yv[3] = __uint_as_float(yo.y & 0xffff0000u);
        yv[4] = __uint_as_float(yo.z << 16); yv[5] = __uint_as_float(yo.z & 0xffff0000u);
        yv[6] = __uint_as_float(yo.w << 16); yv[7] = __uint_as_float(yo.w & 0xffff0000u);
        float r[8];
#pragma unroll
        for (int j = 0; j < 8; ++j) r[j] = gelu_elu(acc0[j] + yv[j]);
        uint4 pk;
        pk.x = (unsigned)bf16_rne(r[0]) | ((unsigned)bf16_rne(r[1]) << 16);
        pk.y = (unsigned)bf16_rne(r[2]) | ((unsigned)bf16_rne(r[3]) << 16);
        pk.z = (unsigned)bf16_rne(r[4]) | ((unsigned)bf16_rne(r[5]) << 16);
        pk.w = (unsigned)bf16_rne(r[6]) | ((unsigned)bf16_rne(r[7]) << 16);
        y[b0] = pk;
    } else {
        // k 16..19: uint2 per lane; row = 320 uint2, offs 256..319
        const uint2* h = reinterpret_cast<const uint2*>(H1u + (size_t)br * H1S);
        uint2*       y = reinterpret_cast<uint2*>(Yu + (size_t)br * H1S);
        int off = 256 + lane;
        float4 a0 = {0,0,0,0}, a1 = {0,0,0,0};
        int e = s0;
        for (; e + 4 <= s1; e += 4) {
            int   iA = src[e],   iB = src[e+1], iC = src[e+2], iD = src[e+3];
            float wA = wts[e],   wB = wts[e+1], wC = wts[e+2], wD = wts[e+3];
            uint2 u0 = h[iA * 320 + off];
            uint2 u1 = h[iB * 320 + off];
            uint2 u2 = h[iC * 320 + off];
            uint2 u3 = h[iD * 320 + off];
            fma4(a0, wA, ubf4(u0)); fma4(a1, wB, ubf4(u1));
            fma4(a0, wC, ubf4(u2)); fma4(a1, wD, ubf4(u3));
        }
        for (; e < s1; ++e) fma4(a0, wts[e], ubf4(h[src[e] * 320 + off]));
        a0.x += a1.x; a0.y += a1.y; a0.z += a1.z; a0.w += a1.w;

        size_t b0 = (size_t)n * 320 + off;
        float4 xv = ubf4(y[b0]);
        float4 r;
        r.x = gelu_elu(a0.x + xv.x);
        r.y = gelu_elu(a0.y + xv.y);
        r.z = gelu_elu(a0.z + xv.z);
        r.w = gelu_elu(a0.w + xv.w);
        uint2 pk;
        pk.x = (unsigned)bf16_rne(r.x) | ((unsigned)bf16_rne(r.y) << 16);
        pk.y = (unsigned)bf16_rne(r.z) | ((unsigned)bf16_rne(r.w) << 16);
        y[b0] = pk;
    }
}

// ---------------- batched dual GEMM2: [M,20]@[20,7] x2; Y bf16 in, H2 bf16 out ----------------
__global__ __launch_bounds__(256) void gemm2_all(
    const unsigned short* __restrict__ Yu, const float* __restrict__ W2,
    const float* __restrict__ V2, const float* __restrict__ b2,
    unsigned short* __restrict__ H2u, float* __restrict__ YV)
{
    int br = blockIdx.y;
    const unsigned short* y = Yu + (size_t)br * H1S;
    unsigned short* h2 = H2u + (size_t)br * H2S;
    float* yv = YV + (size_t)br * YVS;
    __shared__ float w2s[140], v2s[140], b2s[7];
    int t = threadIdx.x;
    if (t < 140) { w2s[t] = W2[br * 140 + t]; v2s[t] = V2[br * 140 + t]; }
    if (t < 7) b2s[t] = b2[br * 7 + t];
    __syncthreads();
    int wv = __builtin_amdgcn_readfirstlane(t >> 6), b = t & 63;
    int n = blockIdx.x * 4 + wv;
    size_t yb = (size_t)n * 1280 + b;
    float yr[20];
#pragma unroll
    for (int k = 0; k < 20; ++k)
        yr[k] = __uint_as_float((unsigned)y[yb + (size_t)k * 64] << 16);
    float a[7] = {}, v[7] = {};
#pragma unroll
    for (int k = 0; k < 20; ++k) {
        float yk = yr[k];
#pragma unroll
        for (int c = 0; c < 7; ++c) {
            a[c] += yk * w2s[k * 7 + c];
            v[c] += yk * v2s[k * 7 + c];
        }
    }
    size_t hb = (size_t)n * 512 + b;
#pragma unroll
    for (int c = 0; c < 7; ++c) h2[hb + (size_t)c * 64] = bf16_rne(a[c]);
    h2[hb + 7 * 64] = 0;                          // padding channel
    size_t vb = (size_t)n * 448 + b;
#pragma unroll
    for (int c = 0; c < 7; ++c) yv[vb + (size_t)c * 64] = v[c] + b2s[c];
}

// ---------------- batched SpMM2 + ReLU + softmax(B) -> per-branch P ----------------
// ONE uint4/lane covers the FULL 1KB row (8ch x 64b bf16). Lane l: c=l>>3,
// b-segment=(l&7)*8. Softmax over b = 8-lane group x 8 local. 6 XCD-pinned
// 2.1MB branch slices; scalarized CSR; 4-deep gather.
__global__ __launch_bounds__(256) void spmm2_all(
    const unsigned short* __restrict__ H2u, const float* __restrict__ YV,
    const int* __restrict__ rowptr, const int* __restrict__ csrc, const float* __restrict__ csrw,
    float* __restrict__ P)
{
    int bid = blockIdx.x;
    int w0 = (bid & 7) * 384 + (bid >> 3);    // 0..3071
    int br = w0 >> 9;                          // 0..5
    int ng = w0 & 511;

    int gg = br == 1 ? 1 : br == 2 ? 2 : br == 5 ? 3 : 0;
    const int*   rp  = rowptr + gg * (NN + 1);
    const int*   src = csrc + (size_t)gg * EE;
    const float* wts = csrw + (size_t)gg * EE;
    const uint4* h2 = reinterpret_cast<const uint4*>(H2u + (size_t)br * H2S);  // 64 uint4/row
    const float* yv = YV + (size_t)br * YVS;
    float* p = P + (size_t)br * YVS;

    int wv = __builtin_amdgcn_readfirstlane(threadIdx.x >> 6);
    int lane = threadIdx.x & 63;
    int n = ng * 4 + wv;
    int c = lane >> 3;               // 0..7 (7 = padding)
    int bseg = (lane & 7) * 8;       // 8 consecutive b
    int s0 = rp[n], s1 = rp[n + 1];

    float acc0[8] = {}, acc1[8] = {};
    int e = s0;
    for (; e + 4 <= s1; e += 4) {
        int   iA = src[e],   iB = src[e+1], iC = src[e+2], iD = src[e+3];
        float wA = wts[e],   wB = wts[e+1], wC = wts[e+2], wD = wts[e+3];
        uint4 u0 = h2[iA * 64 + lane];
        uint4 u1 = h2[iB * 64 + lane];
        uint4 u2 = h2[iC * 64 + lane];
        uint4 u3 = h2[iD * 64 + lane];
        fma8(acc0, wA, u0); fma8(acc1, wB, u1);
        fma8(acc0, wC, u2); fma8(acc1, wD, u3);
    }
    for (; e < s1; ++e) fma8(acc0, wts[e], h2[src[e] * 64 + lane]);
#pragma unroll
    for (int j = 0; j < 8; ++j) acc0[j] += acc1[j];

    float z[8];
    if (c < 7) {
        const float* yp = &yv[(size_t)n * 448 + c * 64 + bseg];
        float4 y0 = *reinterpret_cast<const float4*>(yp);
        float4 y1 = *reinterpret_cast<const float4*>(yp + 4);
        z[0] = fmaxf(acc0[0] + y0.x, 0.0f); z[1] = fmaxf(acc0[1] + y0.y, 0.0f);
        z[2] = fmaxf(acc0[2] + y0.z, 0.0f); z[3] = fmaxf(acc0[3] + y0.w, 0.0f);
        z[4] = fmaxf(acc0[4] + y1.x, 0.0f); z[5] = fmaxf(acc0[5] + y1.y, 0.0f);
        z[6] = fmaxf(acc0[6] + y1.z, 0.0f); z[7] = fmaxf(acc0[7] + y1.w, 0.0f);
    } else {
#pragma unroll
        for (int j = 0; j < 8; ++j) z[j] = 0.0f;
    }
    // softmax over batch: 8 lanes (same c) x 8 locals
    float m = z[0];
#pragma unroll
    for (int j = 1; j < 8; ++j) m = fmaxf(m, z[j]);
#pragma unroll
    for (int o = 4; o > 0; o >>= 1) m = fmaxf(m, __shfl_xor(m, o, 64));
    float pz[8]; float sm = 0.0f;
#pragma unroll
    for (int j = 0; j < 8; ++j) { pz[j] = expf(z[j] - m); sm += pz[j]; }
#pragma unroll
    for (int o = 4; o > 0; o >>= 1) sm += __shfl_xor(sm, o, 64);
    float inv = 1.0f / sm;
    if (c < 7) {
        float* pp = &p[(size_t)n * 448 + c * 64 + bseg];
        float4 r0 = { pz[0] * inv, pz[1] * inv, pz[2] * inv, pz[3] * inv };
        float4 r1 = { pz[4] * inv, pz[5] * inv, pz[6] * inv, pz[7] * inv };
        *reinterpret_cast<float4*>(pp) = r0;
        *reinterpret_cast<float4*>(pp + 4) = r1;
    }
}

// ---------------- wave softmax over 64 lanes (batch axis) ----------------
__device__ __forceinline__ void wave_softmax7(float* z)
{
#pragma unroll
    for (int c = 0; c < 7; ++c) {
        float m = z[c];
#pragma unroll
        for (int o = 32; o > 0; o >>= 1) m = fmaxf(m, __shfl_xor(m, o, 64));
        float p = expf(z[c] - m);
        float s = p;
#pragma unroll
        for (int o = 32; o > 0; o >>= 1) s += __shfl_xor(s, o, 64);
        z[c] = p / s;
    }
}

// ---------------- final: o_lt tail, dense+gnn heads, output [N][C][B] ----------------
__global__ __launch_bounds__(256) void combine_kernel(
    const float* __restrict__ T, const float* __restrict__ P,
    const float* __restrict__ Wl2, const float* __restrict__ bl2,
    const float* __restrict__ Wd, const float* __restrict__ bd,
    const float* __restrict__ Wg, const float* __restrict__ bg,
    float* __restrict__ out)
{
    __shared__ float wl2s[280], bl2s[7], wds[49], bds[7], wgs[49], bgs[7];
    int t = threadIdx.x;
    for (int i = t; i < 280; i += 256) wl2s[i] = Wl2[i];
    if (t < 49) { wds[t] = Wd[t]; wgs[t] = Wg[t]; }
    if (t < 7) { bl2s[t] = bl2[t]; bds[t] = bd[t]; bgs[t] = bg[t]; }
    __syncthreads();

    int wv = t >> 6, b = t & 63;
    int n = blockIdx.x * 4 + wv;
    size_t rbase = (size_t)n * 2560 + b;   // T is [n][40][b]
    float tr[40];
#pragma unroll
    for (int j = 0; j < 40; ++j) tr[j] = T[rbase + (size_t)j * 64];

    float u[7];
#pragma unroll
    for (int c = 0; c < 7; ++c) u[c] = bl2s[c];
    for (int j = 0; j < 40; ++j) {
        float tv = tr[j];
#pragma unroll
        for (int c = 0; c < 7; ++c) u[c] += tv * wl2s[j * 7 + c];
    }
    wave_softmax7(u);   // o_lt

    size_t sbase = (size_t)n * 448 + b;
    float sd[7], sg[7];
#pragma unroll
    for (int c = 0; c < 7; ++c) {
        size_t o = sbase + (size_t)c * 64;
        sg[c] = P[o] + P[YVS + o] + P[2 * YVS + o] + P[3 * YVS + o] + P[4 * YVS + o];
        sd[c] = 2.0f * P[5 * YVS + o] + 2.0f * u[c];
    }
    float dv[7];
#pragma unroll
    for (int c = 0; c < 7; ++c) dv[c] = bds[c];
#pragma unroll
    for (int c2 = 0; c2 < 7; ++c2) {
        float s = sd[c2];
#pragma unroll
        for (int c = 0; c < 7; ++c) dv[c] += s * wds[c2 * 7 + c];
    }
    wave_softmax7(dv);  // out_dense

    float gv[7];
#pragma unroll
    for (int c = 0; c < 7; ++c) gv[c] = bgs[c];
#pragma unroll
    for (int c2 = 0; c2 < 7; ++c2) {
        float s = sg[c2];
#pragma unroll
        for (int c = 0; c < 7; ++c) gv[c] += s * wgs[c2 * 7 + c];
    }
    wave_softmax7(gv);  // out_gnn

    size_t ob = (size_t)n * 448 + b;
#pragma unroll
    for (int c = 0; c < 7; ++c) out[ob + (size_t)c * 64] = dv[c] + gv[c];
}

// ---------------- host ----------------
extern "C" void kernel_launch(void* const* d_in, const int* in_sizes, int n_in,
                              void* d_out, int out_size, void* d_ws, size_t ws_size,
                              hipStream_t stream)
{
    (void)in_sizes; (void)n_in; (void)out_size; (void)ws_size;
    const int* e0 = (const int*)d_in[0];
    const int* e1 = (const int*)d_in[1];
    const int* e2 = (const int*)d_in[2];
    const int* e3 = (const int*)d_in[3];
    const float* X0 = (const float*)d_in[4];
    const float* X1 = (const float*)d_in[5];
    const float* X2 = (const float*)d_in[6];
    const float* X3 = (const float*)d_in[7];
    const float* X4 = (const float*)d_in[8];
    const float* X5 = (const float*)d_in[9];
    const float* W1  = (const float*)d_in[10];
    const float* V1  = (const float*)d_in[11];
    const float* b1  = (const float*)d_in[12];
    const float* W2  = (const float*)d_in[13];
    const float* V2  = (const float*)d_in[14];
    const float* b2  = (const float*)d_in[15];
    const float* Wlt = (const float*)d_in[16];
    const float* blt = (const float*)d_in[17];
    const float* Wl2 = (const float*)d_in[18];
    const float* bl2 = (const float*)d_in[19];
    const float* Wd  = (const float*)d_in[20];
    const float* bd  = (const float*)d_in[21];
    const float* Wg  = (const float*)d_in[22];
    const float* bg  = (const float*)d_in[23];

    char* ws = (char*)d_ws;
    int*   deg    = (int*)(ws + OFF_DEG);
    int*   cursor = (int*)(ws + OFF_CURSOR);
    float* dinv   = (float*)(ws + OFF_DINV);
    int*   rowptr = (int*)(ws + OFF_ROWPTR);
    int*   csrc   = (int*)(ws + OFF_CSRC);
    float* csrw   = (float*)(ws + OFF_CSRW);
    unsigned short* H1u = (unsigned short*)(ws + OFF_H1);
    float* Pbuf   = (float*)(ws + OFF_P);
    unsigned short* Yu = (unsigned short*)(ws + OFF_Y);
    unsigned short* H2u = (unsigned short*)(ws + OFF_H2);
    float* YV     = (float*)(ws + OFF_YV);
    float* Tbuf   = (float*)(ws + OFF_T);

    hipMemsetAsync(d_ws, 0, ZBYTES, stream);

    count_deg_kernel<<<1024, 256, 0, stream>>>(e0 + EE, e1 + EE, e2 + EE, e3 + EE, deg);
    scan_dinv_kernel<<<4, 256, 0, stream>>>(deg, rowptr, dinv);
    fill_csr_kernel<<<1024, 256, 0, stream>>>(e0, e0 + EE, e1, e1 + EE, e2, e2 + EE,
                                              e3, e3 + EE, rowptr, cursor, dinv, csrc, csrw);

    gemm48_mfma<<<dim3(512, 7), 256, 0, stream>>>(X0, X1, X2, X3, X4, X5,
                                                  W1, V1, b1, Wlt, blt, H1u, Yu, Tbuf);
    spmm1_all<<<9216, 256, 0, stream>>>(H1u, Yu, rowptr, csrc, csrw);
    gemm2_all<<<dim3(512, 6), 256, 0, stream>>>(Yu, W2, V2, b2, H2u, YV);
    spmm2_all<<<3072, 256, 0, stream>>>(H2u, YV, rowptr, csrc, csrw, Pbuf);
    combine_kernel<<<512, 256, 0, stream>>>(Tbuf, Pbuf, Wl2, bl2, Wd, bd, Wg, bg,
                                            (float*)d_out);
}